// Round 14
// baseline (881.200 us; speedup 1.0000x reference)
//
#include <hip/hip_runtime.h>

// GCN: h1 = relu(GCNConv(x,W1,b1)); s1 = pool(h1); h2 = relu(GCNConv(h1,W2,b2)); s2 = pool(h2)
// out = [h2 (N*64) | per-graph rows [s1(64) s2(64)] (G*128)]
// r14: 6 dispatches. r13 structure, plus:
//  - pool layer-1 folded into gemm2 dispatch (64 extra blocks; independent).
//  - pool layer-2 folded into agg2 via per-graph completion counters:
//    h2 written with agent-scope atomic stores (coalesced, L2-bypass),
//    __syncthreads drains vmcnt, thread0 bumps gdone[g]; completing block
//    pools graph g with agent-scope atomic loads. No barriers, no polling.

#define FDIM 64
#define BSHIFT 7                 // 128 nodes per bucket
#define MAXNB 1024               // max buckets (N <= 131072)
#define EBCAP 2048               // ebuf slots per bucket
#define COLCAP 3072              // col slots per bucket
#define BCAP 4096                // LDS ints for one bucket's padded col region

__device__ __forceinline__ unsigned short f2bf(float f) {   // RNE
    union { float f; unsigned int u; } a; a.f = f;
    unsigned int u = a.u;
    unsigned int r = u + 0x7fffu + ((u >> 16) & 1u);
    return (unsigned short)(r >> 16);
}
__device__ __forceinline__ float bf2f(unsigned short s) {
    union { unsigned int u; float f; } a; a.u = ((unsigned int)s) << 16;
    return a.f;
}

// ---- D1: gemm1u (bx<gemmB) | bscat | graph bounds — independent ranges ----
__global__ __launch_bounds__(256, 4) void k_pre(
    const int* __restrict__ src, const int* __restrict__ dstp, int E,
    const int* __restrict__ batch, int N, int G, int gemmB, int scatB,
    const float* __restrict__ x, const float* __restrict__ W1,
    int* __restrict__ bucketFill, int* __restrict__ gstart,
    unsigned short* __restrict__ gb1, unsigned int* __restrict__ ebuf) {
    __shared__ __align__(16) char sm[33792];
    int tid = threadIdx.x;
    int bx = blockIdx.x;
    if (bx < gemmB) {
        float4* Ws = (float4*)sm;
        float (*Xs)[68] = (float(*)[68])(sm + 16384);
        ushort4* GB4 = (ushort4*)gb1;
        if (bx == 0 && tid < 16) GB4[(size_t)N * 16 + tid] = make_ushort4(0, 0, 0, 0);
        const float4* W4 = (const float4*)W1;
        for (int i = tid; i < 1024; i += 256) Ws[i] = W4[i];
        int rowBase = bx * 64;
        for (int i = tid; i < 1024; i += 256) {
            int r = i >> 4, f4 = i & 15;
            float4 v = make_float4(0.f, 0.f, 0.f, 0.f);
            if (rowBase + r < N) v = ((const float4*)x)[(size_t)(rowBase + r) * 16 + f4];
            *(float4*)&Xs[r][f4 * 4] = v;
        }
        __syncthreads();
        int r0 = (tid >> 4) * 4;
        int c4 = tid & 15;
        float4 acc0 = make_float4(0,0,0,0), acc1 = acc0, acc2 = acc0, acc3 = acc0;
#pragma unroll 16
        for (int k = 0; k < 64; k++) {
            float4 w = Ws[k * 16 + c4];
            float x0 = Xs[r0 + 0][k], x1 = Xs[r0 + 1][k], x2 = Xs[r0 + 2][k], x3 = Xs[r0 + 3][k];
            acc0.x += x0 * w.x; acc0.y += x0 * w.y; acc0.z += x0 * w.z; acc0.w += x0 * w.w;
            acc1.x += x1 * w.x; acc1.y += x1 * w.y; acc1.z += x1 * w.z; acc1.w += x1 * w.w;
            acc2.x += x2 * w.x; acc2.y += x2 * w.y; acc2.z += x2 * w.z; acc2.w += x2 * w.w;
            acc3.x += x3 * w.x; acc3.y += x3 * w.y; acc3.z += x3 * w.z; acc3.w += x3 * w.w;
        }
        float4 a[4] = {acc0, acc1, acc2, acc3};
#pragma unroll
        for (int i = 0; i < 4; i++) {
            int row = rowBase + r0 + i;
            if (row < N) {
                ushort4 pk;
                pk.x = f2bf(a[i].x); pk.y = f2bf(a[i].y);
                pk.z = f2bf(a[i].z); pk.w = f2bf(a[i].w);
                GB4[(size_t)row * 16 + c4] = pk;
            }
        }
        return;
    }
    if (bx < gemmB + scatB) {
        int* hist = (int*)sm;            // [MAXNB]
        int* base = hist + MAXNB;        // [MAXNB]
        for (int i = tid; i < MAXNB; i += 256) hist[i] = 0;
        __syncthreads();
        int e0 = (bx - gemmB) * 4096;
        int s[16], d[16], r[16];
#pragma unroll
        for (int k = 0; k < 16; k++) {
            int e = e0 + k * 256 + tid;
            bool valid = e < E;
            s[k] = valid ? src[e] : 0;
            d[k] = valid ? dstp[e] : 0;
            r[k] = valid ? atomicAdd(&hist[d[k] >> BSHIFT], 1) : 0;
        }
        __syncthreads();
        for (int i = tid; i < MAXNB; i += 256) {
            int c = hist[i];
            base[i] = c ? (i << 11) + atomicAdd(&bucketFill[i], c) : 0;
        }
        __syncthreads();
#pragma unroll
        for (int k = 0; k < 16; k++) {
            int e = e0 + k * 256 + tid;
            if (e < E)
                ebuf[base[d[k] >> BSHIFT] + r[k]] =
                    (unsigned int)s[k] | ((unsigned int)(d[k] & 127) << 17);
        }
        return;
    }
    int i = (bx - gemmB - scatB) * 256 + tid;
    if (i < N) {
        int b = batch[i];
        if (i == 0) { for (int g = 0; g <= b; g++) gstart[g] = 0; }
        else {
            int pp = batch[i - 1];
            for (int g = pp + 1; g <= b; g++) gstart[g] = i;
        }
        if (i == N - 1) { for (int g = b + 1; g <= G; g++) gstart[g] = N; }
    }
}

// ---- D2: per-bucket padded-CSR finalize in LDS + in-place dinv scale of gb1 ----
__global__ __launch_bounds__(256) void k_bsort(const unsigned int* __restrict__ ebuf,
                                               const int* __restrict__ bucketFill, int N,
                                               int* __restrict__ row_ptr,
                                               int* __restrict__ row_blocks,
                                               int* __restrict__ col,
                                               float* __restrict__ dinv,
                                               unsigned short* __restrict__ gb1) {
    __shared__ int cntL[128];
    __shared__ int scanL[128];
    __shared__ int fillL[128];
    __shared__ int colL[BCAP];
    __shared__ int padT;
    int b = blockIdx.x;
    int n0 = b << BSHIFT;
    int nCnt = N - n0; if (nCnt > 128) nCnt = 128;
    int t = threadIdx.x;
    if (b == 0 && t == 0) dinv[N] = 0.f;
    int cnt = bucketFill[b]; if (cnt > EBCAP) cnt = EBCAP;
    int lo = b << 11, hi = lo + cnt;
    int outBase = b * COLCAP;
    if (t < 128) { cntL[t] = 0; fillL[t] = 0; }
    __syncthreads();
    for (int e = lo + t; e < hi; e += 256)
        atomicAdd(&cntL[ebuf[e] >> 17], 1);
    __syncthreads();
    int pc = 0;
    if (t < 128) { pc = (cntL[t] + 7) & ~7; scanL[t] = pc; }
    __syncthreads();
    for (int off = 1; off < 128; off <<= 1) {
        int u = (t >= off && t < 128) ? scanL[t - off] : 0;
        __syncthreads();
        if (t < 128) scanL[t] += u;
        __syncthreads();
    }
    if (t == 127) padT = scanL[127];
    if (t < nCnt) {
        int ex = scanL[t] - pc;
        row_ptr[n0 + t] = outBase + ex;
        row_blocks[n0 + t] = pc >> 3;
        dinv[n0 + t] = rsqrtf((float)cntL[t] + 1.0f);
        scanL[t] = ex;
    }
    __syncthreads();
    int padTotal = padT;
    if (padTotal <= BCAP) {
        for (int i = t; i < padTotal; i += 256) colL[i] = N;
        __syncthreads();
        for (int e = lo + t; e < hi; e += 256) {
            unsigned int pr = ebuf[e];
            int d = pr >> 17;
            int r = scanL[d] + atomicAdd(&fillL[d], 1);
            colL[r] = (int)(pr & 0x1FFFFu);
        }
        __syncthreads();
        for (int i = t; i < padTotal; i += 256) col[outBase + i] = colL[i];
    } else {
        for (int e = lo + t; e < hi; e += 256) {
            unsigned int pr = ebuf[e];
            int d = pr >> 17;
            int r = scanL[d] + atomicAdd(&fillL[d], 1);
            col[outBase + r] = (int)(pr & 0x1FFFFu);
        }
        __syncthreads();
        if (t < nCnt) {
            int pcl = (cntL[t] + 7) & ~7;
            for (int i = cntL[t]; i < pcl; i++) col[outBase + scanL[t] + i] = N;
        }
    }
    __syncthreads();
    ushort4* GB4 = (ushort4*)gb1;
    for (int i = t; i < nCnt * 16; i += 256) {
        int row = i >> 4, u4 = i & 15;
        float dn = rsqrtf((float)cntL[row] + 1.0f);
        size_t idx = (size_t)(n0 + row) * 16 + u4;
        ushort4 u = GB4[idx];
        u.x = f2bf(bf2f(u.x) * dn);
        u.y = f2bf(bf2f(u.y) * dn);
        u.z = f2bf(bf2f(u.z) * dn);
        u.w = f2bf(bf2f(u.w) * dn);
        GB4[idx] = u;
    }
}

// ---- D3: agg layer 1 (pure gather, bf16 out) ----
__global__ __launch_bounds__(256) void k_agg1(
    const unsigned short* __restrict__ Gb,
    const int* __restrict__ row_ptr, const int* __restrict__ row_blocks,
    const int* __restrict__ col, const float* __restrict__ dinv,
    const float* __restrict__ bias, int N, unsigned short* __restrict__ Out) {
    int w = threadIdx.x >> 6;
    int c = threadIdx.x & 63;
    int n = blockIdx.x * 4 + w;
    if (n >= N) return;
    int e = row_ptr[n];
    int nb8 = row_blocks[n];
    float acc = bf2f(Gb[(size_t)n * FDIM + c]);
    for (; nb8 >= 2; nb8 -= 2, e += 16) {
        int4 ca = *(const int4*)(col + e);
        int4 cb = *(const int4*)(col + e + 4);
        int4 cc = *(const int4*)(col + e + 8);
        int4 cd = *(const int4*)(col + e + 12);
        int s0  = __builtin_amdgcn_readfirstlane(ca.x);
        int s1  = __builtin_amdgcn_readfirstlane(ca.y);
        int s2  = __builtin_amdgcn_readfirstlane(ca.z);
        int s3  = __builtin_amdgcn_readfirstlane(ca.w);
        int s4  = __builtin_amdgcn_readfirstlane(cb.x);
        int s5  = __builtin_amdgcn_readfirstlane(cb.y);
        int s6  = __builtin_amdgcn_readfirstlane(cb.z);
        int s7  = __builtin_amdgcn_readfirstlane(cb.w);
        int s8  = __builtin_amdgcn_readfirstlane(cc.x);
        int s9  = __builtin_amdgcn_readfirstlane(cc.y);
        int s10 = __builtin_amdgcn_readfirstlane(cc.z);
        int s11 = __builtin_amdgcn_readfirstlane(cc.w);
        int s12 = __builtin_amdgcn_readfirstlane(cd.x);
        int s13 = __builtin_amdgcn_readfirstlane(cd.y);
        int s14 = __builtin_amdgcn_readfirstlane(cd.z);
        int s15 = __builtin_amdgcn_readfirstlane(cd.w);
        float a0  = bf2f(Gb[(size_t)s0  * FDIM + c]);
        float a1  = bf2f(Gb[(size_t)s1  * FDIM + c]);
        float a2  = bf2f(Gb[(size_t)s2  * FDIM + c]);
        float a3  = bf2f(Gb[(size_t)s3  * FDIM + c]);
        float a4  = bf2f(Gb[(size_t)s4  * FDIM + c]);
        float a5  = bf2f(Gb[(size_t)s5  * FDIM + c]);
        float a6  = bf2f(Gb[(size_t)s6  * FDIM + c]);
        float a7  = bf2f(Gb[(size_t)s7  * FDIM + c]);
        float a8  = bf2f(Gb[(size_t)s8  * FDIM + c]);
        float a9  = bf2f(Gb[(size_t)s9  * FDIM + c]);
        float a10 = bf2f(Gb[(size_t)s10 * FDIM + c]);
        float a11 = bf2f(Gb[(size_t)s11 * FDIM + c]);
        float a12 = bf2f(Gb[(size_t)s12 * FDIM + c]);
        float a13 = bf2f(Gb[(size_t)s13 * FDIM + c]);
        float a14 = bf2f(Gb[(size_t)s14 * FDIM + c]);
        float a15 = bf2f(Gb[(size_t)s15 * FDIM + c]);
        acc += (((a0 + a1) + (a2 + a3)) + ((a4 + a5) + (a6 + a7)))
             + (((a8 + a9) + (a10 + a11)) + ((a12 + a13) + (a14 + a15)));
    }
    if (nb8) {
        int4 ca = *(const int4*)(col + e);
        int4 cb = *(const int4*)(col + e + 4);
        int s0 = __builtin_amdgcn_readfirstlane(ca.x);
        int s1 = __builtin_amdgcn_readfirstlane(ca.y);
        int s2 = __builtin_amdgcn_readfirstlane(ca.z);
        int s3 = __builtin_amdgcn_readfirstlane(ca.w);
        int s4 = __builtin_amdgcn_readfirstlane(cb.x);
        int s5 = __builtin_amdgcn_readfirstlane(cb.y);
        int s6 = __builtin_amdgcn_readfirstlane(cb.z);
        int s7 = __builtin_amdgcn_readfirstlane(cb.w);
        float a0 = bf2f(Gb[(size_t)s0 * FDIM + c]);
        float a1 = bf2f(Gb[(size_t)s1 * FDIM + c]);
        float a2 = bf2f(Gb[(size_t)s2 * FDIM + c]);
        float a3 = bf2f(Gb[(size_t)s3 * FDIM + c]);
        float a4 = bf2f(Gb[(size_t)s4 * FDIM + c]);
        float a5 = bf2f(Gb[(size_t)s5 * FDIM + c]);
        float a6 = bf2f(Gb[(size_t)s6 * FDIM + c]);
        float a7 = bf2f(Gb[(size_t)s7 * FDIM + c]);
        acc += ((a0 + a1) + (a2 + a3)) + ((a4 + a5) + (a6 + a7));
    }
    float v = fmaxf(acc * dinv[n] + bias[c], 0.f);
    Out[(size_t)n * FDIM + c] = f2bf(v);
}

// ---- D4: gemm2 scaled (bx<gemmB) | pool layer-1 (64 extra blocks) ----
__global__ __launch_bounds__(256, 4) void k_gemm2(
    const unsigned short* __restrict__ H1b, const float* __restrict__ W2,
    const float* __restrict__ dinv, int N, int gemmB,
    const int* __restrict__ gstart, float* __restrict__ pool,
    unsigned short* __restrict__ Gb2) {
    __shared__ __align__(16) char sm[33792];
    int tid = threadIdx.x;
    int bx = blockIdx.x;
    if (bx >= gemmB) {                   // pool layer-1 from bf16 h1b
        int g = bx - gemmB;
        int lo = gstart[g], hi = gstart[g + 1];
        int c4 = tid & 15;
        int rl = tid >> 4;
        float4 acc = make_float4(0.f, 0.f, 0.f, 0.f);
        const ushort4* H = (const ushort4*)H1b;
        for (int r = lo + rl; r < hi; r += 16) {
            ushort4 u = H[(size_t)r * 16 + c4];
            acc.x += bf2f(u.x); acc.y += bf2f(u.y);
            acc.z += bf2f(u.z); acc.w += bf2f(u.w);
        }
        float4 (*smp)[16] = (float4(*)[16])sm;
        smp[rl][c4] = acc;
        __syncthreads();
        if (rl == 0) {
            float4 s = smp[0][c4];
#pragma unroll
            for (int k = 1; k < 16; k++) {
                float4 v = smp[k][c4];
                s.x += v.x; s.y += v.y; s.z += v.z; s.w += v.w;
            }
            float* dq = &pool[(size_t)g * 128 + c4 * 4];
            dq[0] = s.x; dq[1] = s.y; dq[2] = s.z; dq[3] = s.w;
            if (lo == hi) {              // empty-graph guard for layer 2
                float* dq2 = dq + 64;
                dq2[0] = 0.f; dq2[1] = 0.f; dq2[2] = 0.f; dq2[3] = 0.f;
            }
        }
        return;
    }
    float4* Ws = (float4*)sm;
    float (*Xs)[68] = (float(*)[68])(sm + 16384);
    ushort4* GB4 = (ushort4*)Gb2;
    if (bx == 0 && tid < 16)
        GB4[(size_t)N * 16 + tid] = make_ushort4(0, 0, 0, 0);
    const float4* W4 = (const float4*)W2;
    for (int i = tid; i < 1024; i += 256) Ws[i] = W4[i];
    int rowBase = bx * 64;
    const ushort4* H4 = (const ushort4*)H1b;
    for (int i = tid; i < 1024; i += 256) {
        int r = i >> 4, u4 = i & 15;
        float4 v = make_float4(0.f, 0.f, 0.f, 0.f);
        if (rowBase + r < N) {
            ushort4 u = H4[(size_t)(rowBase + r) * 16 + u4];
            v = make_float4(bf2f(u.x), bf2f(u.y), bf2f(u.z), bf2f(u.w));
        }
        *(float4*)&Xs[r][u4 * 4] = v;
    }
    __syncthreads();
    int r0 = (tid >> 4) * 4;
    int c4 = tid & 15;
    float4 acc0 = make_float4(0,0,0,0), acc1 = acc0, acc2 = acc0, acc3 = acc0;
#pragma unroll 16
    for (int k = 0; k < 64; k++) {
        float4 w = Ws[k * 16 + c4];
        float x0 = Xs[r0 + 0][k], x1 = Xs[r0 + 1][k], x2 = Xs[r0 + 2][k], x3 = Xs[r0 + 3][k];
        acc0.x += x0 * w.x; acc0.y += x0 * w.y; acc0.z += x0 * w.z; acc0.w += x0 * w.w;
        acc1.x += x1 * w.x; acc1.y += x1 * w.y; acc1.z += x1 * w.z; acc1.w += x1 * w.w;
        acc2.x += x2 * w.x; acc2.y += x2 * w.y; acc2.z += x2 * w.z; acc2.w += x2 * w.w;
        acc3.x += x3 * w.x; acc3.y += x3 * w.y; acc3.z += x3 * w.z; acc3.w += x3 * w.w;
    }
    float4 a[4] = {acc0, acc1, acc2, acc3};
#pragma unroll
    for (int i = 0; i < 4; i++) {
        int row = rowBase + r0 + i;
        if (row < N) {
            float dn = dinv[row];
            ushort4 pk;
            pk.x = f2bf(a[i].x * dn);
            pk.y = f2bf(a[i].y * dn);
            pk.z = f2bf(a[i].z * dn);
            pk.w = f2bf(a[i].w * dn);
            GB4[(size_t)row * 16 + c4] = pk;
        }
    }
}

// ---- D5: agg layer 2 -> h2 (agent-scope stores) + fused pool layer-2 via
// per-graph completion counters. ----
__global__ __launch_bounds__(256) void k_agg2(
    const unsigned short* __restrict__ Gb,
    const int* __restrict__ row_ptr, const int* __restrict__ row_blocks,
    const int* __restrict__ col, const float* __restrict__ dinv,
    const float* __restrict__ bias, const int* __restrict__ batch,
    const int* __restrict__ gstart, int* __restrict__ gdone, int N,
    float* __restrict__ Out, float* __restrict__ pool) {
    __shared__ int gid[4];
    __shared__ int pooled[4];
    __shared__ float pacc[4][64];
    int w = threadIdx.x >> 6;
    int c = threadIdx.x & 63;
    int n = blockIdx.x * 4 + w;
    if ((threadIdx.x & 63) == 0) gid[w] = (n < N) ? batch[n] : -1;
    if (n < N) {
        int e = row_ptr[n];
        int nb8 = row_blocks[n];
        float acc = bf2f(Gb[(size_t)n * FDIM + c]);
        for (; nb8 >= 2; nb8 -= 2, e += 16) {
            int4 ca = *(const int4*)(col + e);
            int4 cb = *(const int4*)(col + e + 4);
            int4 cc = *(const int4*)(col + e + 8);
            int4 cd = *(const int4*)(col + e + 12);
            int s0  = __builtin_amdgcn_readfirstlane(ca.x);
            int s1  = __builtin_amdgcn_readfirstlane(ca.y);
            int s2  = __builtin_amdgcn_readfirstlane(ca.z);
            int s3  = __builtin_amdgcn_readfirstlane(ca.w);
            int s4  = __builtin_amdgcn_readfirstlane(cb.x);
            int s5  = __builtin_amdgcn_readfirstlane(cb.y);
            int s6  = __builtin_amdgcn_readfirstlane(cb.z);
            int s7  = __builtin_amdgcn_readfirstlane(cb.w);
            int s8  = __builtin_amdgcn_readfirstlane(cc.x);
            int s9  = __builtin_amdgcn_readfirstlane(cc.y);
            int s10 = __builtin_amdgcn_readfirstlane(cc.z);
            int s11 = __builtin_amdgcn_readfirstlane(cc.w);
            int s12 = __builtin_amdgcn_readfirstlane(cd.x);
            int s13 = __builtin_amdgcn_readfirstlane(cd.y);
            int s14 = __builtin_amdgcn_readfirstlane(cd.z);
            int s15 = __builtin_amdgcn_readfirstlane(cd.w);
            float a0  = bf2f(Gb[(size_t)s0  * FDIM + c]);
            float a1  = bf2f(Gb[(size_t)s1  * FDIM + c]);
            float a2  = bf2f(Gb[(size_t)s2  * FDIM + c]);
            float a3  = bf2f(Gb[(size_t)s3  * FDIM + c]);
            float a4  = bf2f(Gb[(size_t)s4  * FDIM + c]);
            float a5  = bf2f(Gb[(size_t)s5  * FDIM + c]);
            float a6  = bf2f(Gb[(size_t)s6  * FDIM + c]);
            float a7  = bf2f(Gb[(size_t)s7  * FDIM + c]);
            float a8  = bf2f(Gb[(size_t)s8  * FDIM + c]);
            float a9  = bf2f(Gb[(size_t)s9  * FDIM + c]);
            float a10 = bf2f(Gb[(size_t)s10 * FDIM + c]);
            float a11 = bf2f(Gb[(size_t)s11 * FDIM + c]);
            float a12 = bf2f(Gb[(size_t)s12 * FDIM + c]);
            float a13 = bf2f(Gb[(size_t)s13 * FDIM + c]);
            float a14 = bf2f(Gb[(size_t)s14 * FDIM + c]);
            float a15 = bf2f(Gb[(size_t)s15 * FDIM + c]);
            acc += (((a0 + a1) + (a2 + a3)) + ((a4 + a5) + (a6 + a7)))
                 + (((a8 + a9) + (a10 + a11)) + ((a12 + a13) + (a14 + a15)));
        }
        if (nb8) {
            int4 ca = *(const int4*)(col + e);
            int4 cb = *(const int4*)(col + e + 4);
            int s0 = __builtin_amdgcn_readfirstlane(ca.x);
            int s1 = __builtin_amdgcn_readfirstlane(ca.y);
            int s2 = __builtin_amdgcn_readfirstlane(ca.z);
            int s3 = __builtin_amdgcn_readfirstlane(ca.w);
            int s4 = __builtin_amdgcn_readfirstlane(cb.x);
            int s5 = __builtin_amdgcn_readfirstlane(cb.y);
            int s6 = __builtin_amdgcn_readfirstlane(cb.z);
            int s7 = __builtin_amdgcn_readfirstlane(cb.w);
            float a0 = bf2f(Gb[(size_t)s0 * FDIM + c]);
            float a1 = bf2f(Gb[(size_t)s1 * FDIM + c]);
            float a2 = bf2f(Gb[(size_t)s2 * FDIM + c]);
            float a3 = bf2f(Gb[(size_t)s3 * FDIM + c]);
            float a4 = bf2f(Gb[(size_t)s4 * FDIM + c]);
            float a5 = bf2f(Gb[(size_t)s5 * FDIM + c]);
            float a6 = bf2f(Gb[(size_t)s6 * FDIM + c]);
            float a7 = bf2f(Gb[(size_t)s7 * FDIM + c]);
            acc += ((a0 + a1) + (a2 + a3)) + ((a4 + a5) + (a6 + a7));
        }
        float v = fmaxf(acc * dinv[n] + bias[c], 0.f);
        // agent-scope store: coalesced, visible at device coherence point
        __hip_atomic_store(&Out[(size_t)n * FDIM + c], v,
                           __ATOMIC_RELAXED, __HIP_MEMORY_SCOPE_AGENT);
    }
    __syncthreads();   // drains each wave's vmcnt before signaling
    if (threadIdx.x == 0) {
        int done[4]; done[0] = done[1] = done[2] = done[3] = -1;
#pragma unroll
        for (int j = 0; j < 4; j++) pooled[j] = -1;
        for (int j = 0; j < 4; j++) {
            int g = gid[j];
            if (g < 0) continue;
            bool dup = false;
            for (int k = 0; k < j; k++) if (gid[k] == g) dup = true;
            if (dup) continue;
            int cntg = 0;
            for (int k = j; k < 4; k++) if (gid[k] == g) cntg++;
            int old = __hip_atomic_fetch_add(&gdone[g], cntg,
                                             __ATOMIC_RELEASE, __HIP_MEMORY_SCOPE_AGENT);
            int gsize = gstart[g + 1] - gstart[g];
            if (old + cntg == gsize) done[j] = g;
        }
#pragma unroll
        for (int j = 0; j < 4; j++) pooled[j] = done[j];
    }
    __syncthreads();
    for (int j = 0; j < 4; j++) {
        int g = pooled[j];
        if (g < 0) continue;
        int lo = gstart[g], hi = gstart[g + 1];
        int rl = threadIdx.x >> 6;          // 4 row streams
        float acc = 0.f;
        for (int r = lo + rl; r < hi; r += 4)
            acc += __hip_atomic_load(&Out[(size_t)r * FDIM + c],
                                     __ATOMIC_RELAXED, __HIP_MEMORY_SCOPE_AGENT);
        pacc[rl][c] = acc;
        __syncthreads();
        if (rl == 0) {
            float s = pacc[0][c] + pacc[1][c] + pacc[2][c] + pacc[3][c];
            pool[(size_t)g * 128 + 64 + c] = s;
        }
        __syncthreads();
    }
}

static inline size_t align256(size_t x) { return (x + 255) & ~(size_t)255; }

extern "C" void kernel_launch(void* const* d_in, const int* in_sizes, int n_in,
                              void* d_out, int out_size, void* d_ws, size_t ws_size,
                              hipStream_t stream) {
    const float* x     = (const float*)d_in[0];
    const int*   ei    = (const int*)d_in[1];
    const int*   batch = (const int*)d_in[2];
    const float* W1    = (const float*)d_in[3];
    const float* b1    = (const float*)d_in[4];
    const float* W2    = (const float*)d_in[5];
    const float* b2    = (const float*)d_in[6];

    const int N = in_sizes[0] / FDIM;
    const int E = in_sizes[1] / 2;
    const int G = 64;
    const int NB = (N + 127) >> BSHIFT;
    const int* src = ei;
    const int* dst = ei + E;

    char* p = (char*)d_ws;
    int* row_ptr     = (int*)p; p += align256(((size_t)N + 1) * 4);
    int* row_blocks  = (int*)p; p += align256((size_t)N * 4);
    int* col         = (int*)p; p += align256((size_t)NB * COLCAP * 4);
    int* bucketFill  = (int*)p; p += align256(((size_t)MAXNB + 64) * 4);  // fill | gdone
    int* gdone       = bucketFill + MAXNB;
    int* gstart      = (int*)p; p += align256((size_t)(G + 1) * 4);
    float* dinv      = (float*)p; p += align256(((size_t)N + 1) * 4);
    unsigned short* gb1 = (unsigned short*)p; p += align256(((size_t)N + 1) * FDIM * 2);
    unsigned short* gb2 = (unsigned short*)p; p += align256(((size_t)N + 1) * FDIM * 2);
    unsigned short* h1b = (unsigned short*)p; p += align256((size_t)N * FDIM * 2);
    unsigned int* ebuf = (unsigned int*)h1b;  // dead before h1b written

    float* out  = (float*)d_out;
    float* h2   = out;
    float* pool = out + (size_t)N * FDIM;

    hipMemsetAsync(bucketFill, 0, ((size_t)MAXNB + 64) * 4, stream);

    int nbB   = (N + 255) / 256;
    int gemmB = (N + 63) / 64;
    int aggB  = (N + 3) / 4;
    int scatB = (E + 4095) / 4096;

    k_pre<<<gemmB + scatB + nbB, 256, 0, stream>>>(src, dst, E, batch, N, G,
                                                   gemmB, scatB, x, W1,
                                                   bucketFill, gstart, gb1, ebuf);
    k_bsort<<<NB, 256, 0, stream>>>(ebuf, bucketFill, N, row_ptr, row_blocks,
                                    col, dinv, gb1);
    k_agg1<<<aggB, 256, 0, stream>>>(gb1, row_ptr, row_blocks, col, dinv, b1, N, h1b);
    k_gemm2<<<gemmB + G, 256, 0, stream>>>(h1b, W2, dinv, N, gemmB, gstart, pool, gb2);
    k_agg2<<<aggB, 256, 0, stream>>>(gb2, row_ptr, row_blocks, col, dinv, b2,
                                     batch, gstart, gdone, N, h2, pool);
}

// Round 15
// 266.404 us; speedup vs baseline: 3.3078x; 3.3078x over previous
//
#include <hip/hip_runtime.h>

// GCN: h1 = relu(GCNConv(x,W1,b1)); s1 = pool(h1); h2 = relu(GCNConv(h1,W2,b2)); s2 = pool(h2)
// out = [h2 (N*64) | per-graph rows [s1(64) s2(64)] (G*128)]
// r15: 6 dispatches. r13 proven bodies. Pool-1 folded into gemm2 dispatch
// (independent blocks; also zeroes pool-2 slots). Pool-2 folded into agg2 via
// LDS pre-reduce + ~64 coalesced fp32 atomicAdds per block (r14 lesson:
// per-element agent-scope stores are 100x too slow; r11: no grid barriers).

#define FDIM 64
#define BSHIFT 7                 // 128 nodes per bucket
#define MAXNB 1024               // max buckets (N <= 131072)
#define EBCAP 2048               // ebuf slots per bucket
#define COLCAP 3072              // col slots per bucket
#define BCAP 4096                // LDS ints for one bucket's padded col region

__device__ __forceinline__ unsigned short f2bf(float f) {   // RNE
    union { float f; unsigned int u; } a; a.f = f;
    unsigned int u = a.u;
    unsigned int r = u + 0x7fffu + ((u >> 16) & 1u);
    return (unsigned short)(r >> 16);
}
__device__ __forceinline__ float bf2f(unsigned short s) {
    union { unsigned int u; float f; } a; a.u = ((unsigned int)s) << 16;
    return a.f;
}

// ---- D1: gemm1u (bx<gemmB) | bscat | graph bounds — independent ranges ----
__global__ __launch_bounds__(256, 4) void k_pre(
    const int* __restrict__ src, const int* __restrict__ dstp, int E,
    const int* __restrict__ batch, int N, int G, int gemmB, int scatB,
    const float* __restrict__ x, const float* __restrict__ W1,
    int* __restrict__ bucketFill, int* __restrict__ gstart,
    unsigned short* __restrict__ gb1, unsigned int* __restrict__ ebuf) {
    __shared__ __align__(16) char sm[33792];
    int tid = threadIdx.x;
    int bx = blockIdx.x;
    if (bx < gemmB) {
        float4* Ws = (float4*)sm;
        float (*Xs)[68] = (float(*)[68])(sm + 16384);
        ushort4* GB4 = (ushort4*)gb1;
        if (bx == 0 && tid < 16) GB4[(size_t)N * 16 + tid] = make_ushort4(0, 0, 0, 0);
        const float4* W4 = (const float4*)W1;
        for (int i = tid; i < 1024; i += 256) Ws[i] = W4[i];
        int rowBase = bx * 64;
        for (int i = tid; i < 1024; i += 256) {
            int r = i >> 4, f4 = i & 15;
            float4 v = make_float4(0.f, 0.f, 0.f, 0.f);
            if (rowBase + r < N) v = ((const float4*)x)[(size_t)(rowBase + r) * 16 + f4];
            *(float4*)&Xs[r][f4 * 4] = v;
        }
        __syncthreads();
        int r0 = (tid >> 4) * 4;
        int c4 = tid & 15;
        float4 acc0 = make_float4(0,0,0,0), acc1 = acc0, acc2 = acc0, acc3 = acc0;
#pragma unroll 16
        for (int k = 0; k < 64; k++) {
            float4 w = Ws[k * 16 + c4];
            float x0 = Xs[r0 + 0][k], x1 = Xs[r0 + 1][k], x2 = Xs[r0 + 2][k], x3 = Xs[r0 + 3][k];
            acc0.x += x0 * w.x; acc0.y += x0 * w.y; acc0.z += x0 * w.z; acc0.w += x0 * w.w;
            acc1.x += x1 * w.x; acc1.y += x1 * w.y; acc1.z += x1 * w.z; acc1.w += x1 * w.w;
            acc2.x += x2 * w.x; acc2.y += x2 * w.y; acc2.z += x2 * w.z; acc2.w += x2 * w.w;
            acc3.x += x3 * w.x; acc3.y += x3 * w.y; acc3.z += x3 * w.z; acc3.w += x3 * w.w;
        }
        float4 a[4] = {acc0, acc1, acc2, acc3};
#pragma unroll
        for (int i = 0; i < 4; i++) {
            int row = rowBase + r0 + i;
            if (row < N) {
                ushort4 pk;
                pk.x = f2bf(a[i].x); pk.y = f2bf(a[i].y);
                pk.z = f2bf(a[i].z); pk.w = f2bf(a[i].w);
                GB4[(size_t)row * 16 + c4] = pk;
            }
        }
        return;
    }
    if (bx < gemmB + scatB) {
        int* hist = (int*)sm;            // [MAXNB]
        int* base = hist + MAXNB;        // [MAXNB]
        for (int i = tid; i < MAXNB; i += 256) hist[i] = 0;
        __syncthreads();
        int e0 = (bx - gemmB) * 4096;
        int s[16], d[16], r[16];
#pragma unroll
        for (int k = 0; k < 16; k++) {
            int e = e0 + k * 256 + tid;
            bool valid = e < E;
            s[k] = valid ? src[e] : 0;
            d[k] = valid ? dstp[e] : 0;
            r[k] = valid ? atomicAdd(&hist[d[k] >> BSHIFT], 1) : 0;
        }
        __syncthreads();
        for (int i = tid; i < MAXNB; i += 256) {
            int c = hist[i];
            base[i] = c ? (i << 11) + atomicAdd(&bucketFill[i], c) : 0;
        }
        __syncthreads();
#pragma unroll
        for (int k = 0; k < 16; k++) {
            int e = e0 + k * 256 + tid;
            if (e < E)
                ebuf[base[d[k] >> BSHIFT] + r[k]] =
                    (unsigned int)s[k] | ((unsigned int)(d[k] & 127) << 17);
        }
        return;
    }
    int i = (bx - gemmB - scatB) * 256 + tid;
    if (i < N) {
        int b = batch[i];
        if (i == 0) { for (int g = 0; g <= b; g++) gstart[g] = 0; }
        else {
            int pp = batch[i - 1];
            for (int g = pp + 1; g <= b; g++) gstart[g] = i;
        }
        if (i == N - 1) { for (int g = b + 1; g <= G; g++) gstart[g] = N; }
    }
}

// ---- D2: per-bucket padded-CSR finalize in LDS + in-place dinv scale of gb1 ----
__global__ __launch_bounds__(256) void k_bsort(const unsigned int* __restrict__ ebuf,
                                               const int* __restrict__ bucketFill, int N,
                                               int* __restrict__ row_ptr,
                                               int* __restrict__ row_blocks,
                                               int* __restrict__ col,
                                               float* __restrict__ dinv,
                                               unsigned short* __restrict__ gb1) {
    __shared__ int cntL[128];
    __shared__ int scanL[128];
    __shared__ int fillL[128];
    __shared__ int colL[BCAP];
    __shared__ int padT;
    int b = blockIdx.x;
    int n0 = b << BSHIFT;
    int nCnt = N - n0; if (nCnt > 128) nCnt = 128;
    int t = threadIdx.x;
    if (b == 0 && t == 0) dinv[N] = 0.f;
    int cnt = bucketFill[b]; if (cnt > EBCAP) cnt = EBCAP;
    int lo = b << 11, hi = lo + cnt;
    int outBase = b * COLCAP;
    if (t < 128) { cntL[t] = 0; fillL[t] = 0; }
    __syncthreads();
    for (int e = lo + t; e < hi; e += 256)
        atomicAdd(&cntL[ebuf[e] >> 17], 1);
    __syncthreads();
    int pc = 0;
    if (t < 128) { pc = (cntL[t] + 7) & ~7; scanL[t] = pc; }
    __syncthreads();
    for (int off = 1; off < 128; off <<= 1) {
        int u = (t >= off && t < 128) ? scanL[t - off] : 0;
        __syncthreads();
        if (t < 128) scanL[t] += u;
        __syncthreads();
    }
    if (t == 127) padT = scanL[127];
    if (t < nCnt) {
        int ex = scanL[t] - pc;
        row_ptr[n0 + t] = outBase + ex;
        row_blocks[n0 + t] = pc >> 3;
        dinv[n0 + t] = rsqrtf((float)cntL[t] + 1.0f);
        scanL[t] = ex;
    }
    __syncthreads();
    int padTotal = padT;
    if (padTotal <= BCAP) {
        for (int i = t; i < padTotal; i += 256) colL[i] = N;
        __syncthreads();
        for (int e = lo + t; e < hi; e += 256) {
            unsigned int pr = ebuf[e];
            int d = pr >> 17;
            int r = scanL[d] + atomicAdd(&fillL[d], 1);
            colL[r] = (int)(pr & 0x1FFFFu);
        }
        __syncthreads();
        for (int i = t; i < padTotal; i += 256) col[outBase + i] = colL[i];
    } else {
        for (int e = lo + t; e < hi; e += 256) {
            unsigned int pr = ebuf[e];
            int d = pr >> 17;
            int r = scanL[d] + atomicAdd(&fillL[d], 1);
            col[outBase + r] = (int)(pr & 0x1FFFFu);
        }
        __syncthreads();
        if (t < nCnt) {
            int pcl = (cntL[t] + 7) & ~7;
            for (int i = cntL[t]; i < pcl; i++) col[outBase + scanL[t] + i] = N;
        }
    }
    __syncthreads();
    ushort4* GB4 = (ushort4*)gb1;
    for (int i = t; i < nCnt * 16; i += 256) {
        int row = i >> 4, u4 = i & 15;
        float dn = rsqrtf((float)cntL[row] + 1.0f);
        size_t idx = (size_t)(n0 + row) * 16 + u4;
        ushort4 u = GB4[idx];
        u.x = f2bf(bf2f(u.x) * dn);
        u.y = f2bf(bf2f(u.y) * dn);
        u.z = f2bf(bf2f(u.z) * dn);
        u.w = f2bf(bf2f(u.w) * dn);
        GB4[idx] = u;
    }
}

// ---- D3: agg layer 1 (pure gather, bf16 out) ----
__global__ __launch_bounds__(256) void k_agg1(
    const unsigned short* __restrict__ Gb,
    const int* __restrict__ row_ptr, const int* __restrict__ row_blocks,
    const int* __restrict__ col, const float* __restrict__ dinv,
    const float* __restrict__ bias, int N, unsigned short* __restrict__ Out) {
    int w = threadIdx.x >> 6;
    int c = threadIdx.x & 63;
    int n = blockIdx.x * 4 + w;
    if (n >= N) return;
    int e = row_ptr[n];
    int nb8 = row_blocks[n];
    float acc = bf2f(Gb[(size_t)n * FDIM + c]);
    for (; nb8 >= 2; nb8 -= 2, e += 16) {
        int4 ca = *(const int4*)(col + e);
        int4 cb = *(const int4*)(col + e + 4);
        int4 cc = *(const int4*)(col + e + 8);
        int4 cd = *(const int4*)(col + e + 12);
        int s0  = __builtin_amdgcn_readfirstlane(ca.x);
        int s1  = __builtin_amdgcn_readfirstlane(ca.y);
        int s2  = __builtin_amdgcn_readfirstlane(ca.z);
        int s3  = __builtin_amdgcn_readfirstlane(ca.w);
        int s4  = __builtin_amdgcn_readfirstlane(cb.x);
        int s5  = __builtin_amdgcn_readfirstlane(cb.y);
        int s6  = __builtin_amdgcn_readfirstlane(cb.z);
        int s7  = __builtin_amdgcn_readfirstlane(cb.w);
        int s8  = __builtin_amdgcn_readfirstlane(cc.x);
        int s9  = __builtin_amdgcn_readfirstlane(cc.y);
        int s10 = __builtin_amdgcn_readfirstlane(cc.z);
        int s11 = __builtin_amdgcn_readfirstlane(cc.w);
        int s12 = __builtin_amdgcn_readfirstlane(cd.x);
        int s13 = __builtin_amdgcn_readfirstlane(cd.y);
        int s14 = __builtin_amdgcn_readfirstlane(cd.z);
        int s15 = __builtin_amdgcn_readfirstlane(cd.w);
        float a0  = bf2f(Gb[(size_t)s0  * FDIM + c]);
        float a1  = bf2f(Gb[(size_t)s1  * FDIM + c]);
        float a2  = bf2f(Gb[(size_t)s2  * FDIM + c]);
        float a3  = bf2f(Gb[(size_t)s3  * FDIM + c]);
        float a4  = bf2f(Gb[(size_t)s4  * FDIM + c]);
        float a5  = bf2f(Gb[(size_t)s5  * FDIM + c]);
        float a6  = bf2f(Gb[(size_t)s6  * FDIM + c]);
        float a7  = bf2f(Gb[(size_t)s7  * FDIM + c]);
        float a8  = bf2f(Gb[(size_t)s8  * FDIM + c]);
        float a9  = bf2f(Gb[(size_t)s9  * FDIM + c]);
        float a10 = bf2f(Gb[(size_t)s10 * FDIM + c]);
        float a11 = bf2f(Gb[(size_t)s11 * FDIM + c]);
        float a12 = bf2f(Gb[(size_t)s12 * FDIM + c]);
        float a13 = bf2f(Gb[(size_t)s13 * FDIM + c]);
        float a14 = bf2f(Gb[(size_t)s14 * FDIM + c]);
        float a15 = bf2f(Gb[(size_t)s15 * FDIM + c]);
        acc += (((a0 + a1) + (a2 + a3)) + ((a4 + a5) + (a6 + a7)))
             + (((a8 + a9) + (a10 + a11)) + ((a12 + a13) + (a14 + a15)));
    }
    if (nb8) {
        int4 ca = *(const int4*)(col + e);
        int4 cb = *(const int4*)(col + e + 4);
        int s0 = __builtin_amdgcn_readfirstlane(ca.x);
        int s1 = __builtin_amdgcn_readfirstlane(ca.y);
        int s2 = __builtin_amdgcn_readfirstlane(ca.z);
        int s3 = __builtin_amdgcn_readfirstlane(ca.w);
        int s4 = __builtin_amdgcn_readfirstlane(cb.x);
        int s5 = __builtin_amdgcn_readfirstlane(cb.y);
        int s6 = __builtin_amdgcn_readfirstlane(cb.z);
        int s7 = __builtin_amdgcn_readfirstlane(cb.w);
        float a0 = bf2f(Gb[(size_t)s0 * FDIM + c]);
        float a1 = bf2f(Gb[(size_t)s1 * FDIM + c]);
        float a2 = bf2f(Gb[(size_t)s2 * FDIM + c]);
        float a3 = bf2f(Gb[(size_t)s3 * FDIM + c]);
        float a4 = bf2f(Gb[(size_t)s4 * FDIM + c]);
        float a5 = bf2f(Gb[(size_t)s5 * FDIM + c]);
        float a6 = bf2f(Gb[(size_t)s6 * FDIM + c]);
        float a7 = bf2f(Gb[(size_t)s7 * FDIM + c]);
        acc += ((a0 + a1) + (a2 + a3)) + ((a4 + a5) + (a6 + a7));
    }
    float v = fmaxf(acc * dinv[n] + bias[c], 0.f);
    Out[(size_t)n * FDIM + c] = f2bf(v);
}

// ---- D4: gemm2 scaled (bx<gemmB) | pool layer-1 + zero pool layer-2 ----
__global__ __launch_bounds__(256, 4) void k_gemm2(
    const unsigned short* __restrict__ H1b, const float* __restrict__ W2,
    const float* __restrict__ dinv, int N, int gemmB,
    const int* __restrict__ gstart, float* __restrict__ pool,
    unsigned short* __restrict__ Gb2) {
    __shared__ __align__(16) char sm[33792];
    int tid = threadIdx.x;
    int bx = blockIdx.x;
    if (bx >= gemmB) {                   // pool layer-1 from bf16 h1b
        int g = bx - gemmB;
        int lo = gstart[g], hi = gstart[g + 1];
        int c4 = tid & 15;
        int rl = tid >> 4;
        float4 acc = make_float4(0.f, 0.f, 0.f, 0.f);
        const ushort4* H = (const ushort4*)H1b;
        for (int r = lo + rl; r < hi; r += 16) {
            ushort4 u = H[(size_t)r * 16 + c4];
            acc.x += bf2f(u.x); acc.y += bf2f(u.y);
            acc.z += bf2f(u.z); acc.w += bf2f(u.w);
        }
        float4 (*smp)[16] = (float4(*)[16])sm;
        smp[rl][c4] = acc;
        __syncthreads();
        if (rl == 0) {
            float4 s = smp[0][c4];
#pragma unroll
            for (int k = 1; k < 16; k++) {
                float4 v = smp[k][c4];
                s.x += v.x; s.y += v.y; s.z += v.z; s.w += v.w;
            }
            float* dq = &pool[(size_t)g * 128 + c4 * 4];
            dq[0] = s.x; dq[1] = s.y; dq[2] = s.z; dq[3] = s.w;
            float* dq2 = dq + 64;        // zero layer-2 slots for agg2 atomics
            dq2[0] = 0.f; dq2[1] = 0.f; dq2[2] = 0.f; dq2[3] = 0.f;
        }
        return;
    }
    float4* Ws = (float4*)sm;
    float (*Xs)[68] = (float(*)[68])(sm + 16384);
    ushort4* GB4 = (ushort4*)Gb2;
    if (bx == 0 && tid < 16)
        GB4[(size_t)N * 16 + tid] = make_ushort4(0, 0, 0, 0);
    const float4* W4 = (const float4*)W2;
    for (int i = tid; i < 1024; i += 256) Ws[i] = W4[i];
    int rowBase = bx * 64;
    const ushort4* H4 = (const ushort4*)H1b;
    for (int i = tid; i < 1024; i += 256) {
        int r = i >> 4, u4 = i & 15;
        float4 v = make_float4(0.f, 0.f, 0.f, 0.f);
        if (rowBase + r < N) {
            ushort4 u = H4[(size_t)(rowBase + r) * 16 + u4];
            v = make_float4(bf2f(u.x), bf2f(u.y), bf2f(u.z), bf2f(u.w));
        }
        *(float4*)&Xs[r][u4 * 4] = v;
    }
    __syncthreads();
    int r0 = (tid >> 4) * 4;
    int c4 = tid & 15;
    float4 acc0 = make_float4(0,0,0,0), acc1 = acc0, acc2 = acc0, acc3 = acc0;
#pragma unroll 16
    for (int k = 0; k < 64; k++) {
        float4 w = Ws[k * 16 + c4];
        float x0 = Xs[r0 + 0][k], x1 = Xs[r0 + 1][k], x2 = Xs[r0 + 2][k], x3 = Xs[r0 + 3][k];
        acc0.x += x0 * w.x; acc0.y += x0 * w.y; acc0.z += x0 * w.z; acc0.w += x0 * w.w;
        acc1.x += x1 * w.x; acc1.y += x1 * w.y; acc1.z += x1 * w.z; acc1.w += x1 * w.w;
        acc2.x += x2 * w.x; acc2.y += x2 * w.y; acc2.z += x2 * w.z; acc2.w += x2 * w.w;
        acc3.x += x3 * w.x; acc3.y += x3 * w.y; acc3.z += x3 * w.z; acc3.w += x3 * w.w;
    }
    float4 a[4] = {acc0, acc1, acc2, acc3};
#pragma unroll
    for (int i = 0; i < 4; i++) {
        int row = rowBase + r0 + i;
        if (row < N) {
            float dn = dinv[row];
            ushort4 pk;
            pk.x = f2bf(a[i].x * dn);
            pk.y = f2bf(a[i].y * dn);
            pk.z = f2bf(a[i].z * dn);
            pk.w = f2bf(a[i].w * dn);
            GB4[(size_t)row * 16 + c4] = pk;
        }
    }
}

// ---- D5: agg layer 2 -> h2 (plain stores) + pool layer-2 via LDS pre-reduce
// and ~64 coalesced fp32 atomicAdds per block (G12 pattern). ----
__global__ __launch_bounds__(256) void k_agg2(
    const unsigned short* __restrict__ Gb,
    const int* __restrict__ row_ptr, const int* __restrict__ row_blocks,
    const int* __restrict__ col, const float* __restrict__ dinv,
    const float* __restrict__ bias, const int* __restrict__ batch, int N,
    float* __restrict__ Out, float* __restrict__ pool) {
    __shared__ float pacc[4][64];
    __shared__ int gid[4];
    int w = threadIdx.x >> 6;
    int c = threadIdx.x & 63;
    int n = blockIdx.x * 4 + w;
    float v = 0.f;
    if ((threadIdx.x & 63) == 0) gid[w] = (n < N) ? batch[n] : -1;
    if (n < N) {
        int e = row_ptr[n];
        int nb8 = row_blocks[n];
        float acc = bf2f(Gb[(size_t)n * FDIM + c]);
        for (; nb8 >= 2; nb8 -= 2, e += 16) {
            int4 ca = *(const int4*)(col + e);
            int4 cb = *(const int4*)(col + e + 4);
            int4 cc = *(const int4*)(col + e + 8);
            int4 cd = *(const int4*)(col + e + 12);
            int s0  = __builtin_amdgcn_readfirstlane(ca.x);
            int s1  = __builtin_amdgcn_readfirstlane(ca.y);
            int s2  = __builtin_amdgcn_readfirstlane(ca.z);
            int s3  = __builtin_amdgcn_readfirstlane(ca.w);
            int s4  = __builtin_amdgcn_readfirstlane(cb.x);
            int s5  = __builtin_amdgcn_readfirstlane(cb.y);
            int s6  = __builtin_amdgcn_readfirstlane(cb.z);
            int s7  = __builtin_amdgcn_readfirstlane(cb.w);
            int s8  = __builtin_amdgcn_readfirstlane(cc.x);
            int s9  = __builtin_amdgcn_readfirstlane(cc.y);
            int s10 = __builtin_amdgcn_readfirstlane(cc.z);
            int s11 = __builtin_amdgcn_readfirstlane(cc.w);
            int s12 = __builtin_amdgcn_readfirstlane(cd.x);
            int s13 = __builtin_amdgcn_readfirstlane(cd.y);
            int s14 = __builtin_amdgcn_readfirstlane(cd.z);
            int s15 = __builtin_amdgcn_readfirstlane(cd.w);
            float a0  = bf2f(Gb[(size_t)s0  * FDIM + c]);
            float a1  = bf2f(Gb[(size_t)s1  * FDIM + c]);
            float a2  = bf2f(Gb[(size_t)s2  * FDIM + c]);
            float a3  = bf2f(Gb[(size_t)s3  * FDIM + c]);
            float a4  = bf2f(Gb[(size_t)s4  * FDIM + c]);
            float a5  = bf2f(Gb[(size_t)s5  * FDIM + c]);
            float a6  = bf2f(Gb[(size_t)s6  * FDIM + c]);
            float a7  = bf2f(Gb[(size_t)s7  * FDIM + c]);
            float a8  = bf2f(Gb[(size_t)s8  * FDIM + c]);
            float a9  = bf2f(Gb[(size_t)s9  * FDIM + c]);
            float a10 = bf2f(Gb[(size_t)s10 * FDIM + c]);
            float a11 = bf2f(Gb[(size_t)s11 * FDIM + c]);
            float a12 = bf2f(Gb[(size_t)s12 * FDIM + c]);
            float a13 = bf2f(Gb[(size_t)s13 * FDIM + c]);
            float a14 = bf2f(Gb[(size_t)s14 * FDIM + c]);
            float a15 = bf2f(Gb[(size_t)s15 * FDIM + c]);
            acc += (((a0 + a1) + (a2 + a3)) + ((a4 + a5) + (a6 + a7)))
                 + (((a8 + a9) + (a10 + a11)) + ((a12 + a13) + (a14 + a15)));
        }
        if (nb8) {
            int4 ca = *(const int4*)(col + e);
            int4 cb = *(const int4*)(col + e + 4);
            int s0 = __builtin_amdgcn_readfirstlane(ca.x);
            int s1 = __builtin_amdgcn_readfirstlane(ca.y);
            int s2 = __builtin_amdgcn_readfirstlane(ca.z);
            int s3 = __builtin_amdgcn_readfirstlane(ca.w);
            int s4 = __builtin_amdgcn_readfirstlane(cb.x);
            int s5 = __builtin_amdgcn_readfirstlane(cb.y);
            int s6 = __builtin_amdgcn_readfirstlane(cb.z);
            int s7 = __builtin_amdgcn_readfirstlane(cb.w);
            float a0 = bf2f(Gb[(size_t)s0 * FDIM + c]);
            float a1 = bf2f(Gb[(size_t)s1 * FDIM + c]);
            float a2 = bf2f(Gb[(size_t)s2 * FDIM + c]);
            float a3 = bf2f(Gb[(size_t)s3 * FDIM + c]);
            float a4 = bf2f(Gb[(size_t)s4 * FDIM + c]);
            float a5 = bf2f(Gb[(size_t)s5 * FDIM + c]);
            float a6 = bf2f(Gb[(size_t)s6 * FDIM + c]);
            float a7 = bf2f(Gb[(size_t)s7 * FDIM + c]);
            acc += ((a0 + a1) + (a2 + a3)) + ((a4 + a5) + (a6 + a7));
        }
        v = fmaxf(acc * dinv[n] + bias[c], 0.f);
        Out[(size_t)n * FDIM + c] = v;
    }
    pacc[w][c] = v;
    __syncthreads();
    if (w == 0) {       // wave 0: per distinct graph, sum matching rows, 1 atomicAdd/feature
#pragma unroll
        for (int j = 0; j < 4; j++) {
            int g = gid[j];
            if (g < 0) continue;
            bool dup = false;
            for (int k = 0; k < j; k++) if (gid[k] == g) dup = true;
            if (dup) continue;
            float s = 0.f;
            for (int k = j; k < 4; k++) if (gid[k] == g) s += pacc[k][c];
            atomicAdd(&pool[(size_t)g * 128 + 64 + c], s);
        }
    }
}

static inline size_t align256(size_t x) { return (x + 255) & ~(size_t)255; }

extern "C" void kernel_launch(void* const* d_in, const int* in_sizes, int n_in,
                              void* d_out, int out_size, void* d_ws, size_t ws_size,
                              hipStream_t stream) {
    const float* x     = (const float*)d_in[0];
    const int*   ei    = (const int*)d_in[1];
    const int*   batch = (const int*)d_in[2];
    const float* W1    = (const float*)d_in[3];
    const float* b1    = (const float*)d_in[4];
    const float* W2    = (const float*)d_in[5];
    const float* b2    = (const float*)d_in[6];

    const int N = in_sizes[0] / FDIM;
    const int E = in_sizes[1] / 2;
    const int G = 64;
    const int NB = (N + 127) >> BSHIFT;
    const int* src = ei;
    const int* dst = ei + E;

    char* p = (char*)d_ws;
    int* row_ptr     = (int*)p; p += align256(((size_t)N + 1) * 4);
    int* row_blocks  = (int*)p; p += align256((size_t)N * 4);
    int* col         = (int*)p; p += align256((size_t)NB * COLCAP * 4);
    int* bucketFill  = (int*)p; p += align256((size_t)MAXNB * 4);
    int* gstart      = (int*)p; p += align256((size_t)(G + 1) * 4);
    float* dinv      = (float*)p; p += align256(((size_t)N + 1) * 4);
    unsigned short* gb1 = (unsigned short*)p; p += align256(((size_t)N + 1) * FDIM * 2);
    unsigned short* gb2 = (unsigned short*)p; p += align256(((size_t)N + 1) * FDIM * 2);
    unsigned short* h1b = (unsigned short*)p; p += align256((size_t)N * FDIM * 2);
    unsigned int* ebuf = (unsigned int*)h1b;  // dead before h1b written

    float* out  = (float*)d_out;
    float* h2   = out;
    float* pool = out + (size_t)N * FDIM;

    hipMemsetAsync(bucketFill, 0, (size_t)MAXNB * 4, stream);

    int nbB   = (N + 255) / 256;
    int gemmB = (N + 63) / 64;
    int aggB  = (N + 3) / 4;
    int scatB = (E + 4095) / 4096;

    k_pre<<<gemmB + scatB + nbB, 256, 0, stream>>>(src, dst, E, batch, N, G,
                                                   gemmB, scatB, x, W1,
                                                   bucketFill, gstart, gb1, ebuf);
    k_bsort<<<NB, 256, 0, stream>>>(ebuf, bucketFill, N, row_ptr, row_blocks,
                                    col, dinv, gb1);
    k_agg1<<<aggB, 256, 0, stream>>>(gb1, row_ptr, row_blocks, col, dinv, b1, N, h1b);
    k_gemm2<<<gemmB + G, 256, 0, stream>>>(h1b, W2, dinv, N, gemmB, gstart, pool, gb2);
    k_agg2<<<aggB, 256, 0, stream>>>(gb2, row_ptr, row_blocks, col, dinv, b2,
                                     batch, N, h2, pool);
}